// Round 9
// baseline (314.247 us; speedup 1.0000x reference)
//
#include <hip/hip_runtime.h>
#include <stdint.h>

typedef unsigned long long ULL;

// ---------------- prep: conv1 signs + conv2/fc2 bit-packs in ONE kernel ----------------
// waves 0..575: wb2[co*9+tap] bit ci = sign(w2[co][ci][tap])
// waves 576..895: wbf2[n*32+k] bit j = sign(fc2w[n][k*64+j])
// waves 896..904: sgn1 (576 floats +-1)
__global__ __launch_bounds__(256) void prep_small(const float* __restrict__ w1,
        const float* __restrict__ w2, const float* __restrict__ fc2w,
        float* __restrict__ sgn1, ULL* __restrict__ wb2, ULL* __restrict__ wbf2) {
    int wave = threadIdx.x >> 6, lane = threadIdx.x & 63;
    int W = blockIdx.x * 4 + wave;
    if (W < 576) {
        int co = W / 9, tap = W - co * 9;
        ULL wd = __ballot(w2[(co * 64 + lane) * 9 + tap] >= 0.f);
        if (lane == 0) wb2[W] = wd;
    } else if (W < 896) {
        int idx = W - 576;
        int n = idx >> 5, k = idx & 31;
        ULL wd = __ballot(fc2w[n * 2048 + k * 64 + lane] >= 0.f);
        if (lane == 0) wbf2[idx] = wd;
    } else if (W < 905) {
        int i = (W - 896) * 64 + lane;
        if (i < 576) sgn1[i] = (w1[i] >= 0.f) ? 1.f : -1.f;
    }
}

// fc1 weights transposed: wbT[p*2048 + n] bit c = sign(fc1w[n][c*49+p])
// stage 4 contiguous rows in LDS coalesced, ballot from LDS. GRID = 512 blocks.
__global__ __launch_bounds__(256) void prep_pack_fc1(const float* __restrict__ fc1w,
                                                     ULL* __restrict__ wbT) {
    __shared__ float rows[4 * 3136];
    int t = threadIdx.x;
    const float* src = fc1w + (size_t)blockIdx.x * 4 * 3136;
    for (int i = t; i < 4 * 3136; i += 256) rows[i] = src[i];
    __syncthreads();
    int wave = t >> 6, lane = t & 63;
    int n = blockIdx.x * 4 + wave;
    const float* r = rows + wave * 3136 + lane * 49;   // stride 49 % 32 = 17 -> 2-way, free
    for (int p = 0; p < 49; ++p) {
        ULL wd = __ballot(r[p] >= 0.f);
        if (lane == 0) wbT[p * 2048 + n] = wd;
    }
}

// ---------------- k1 v3: conv1 + maxpool + bn1 + binarize -> qact1 bits ----------------
// one block per sample, 7 waves; lane = output channel (weights + BN consts in registers);
// wave = pool rows w and w+7; image column-major zero-padded 30x30 in LDS;
// px loop FULLY UNROLLED -> immediate LDS offsets, no slide movs.
__global__ __launch_bounds__(448, 4) void k1_conv1(const float* __restrict__ x,
        const float* __restrict__ sgn1, const float* __restrict__ b1,
        const float* __restrict__ g, const float* __restrict__ be,
        const float* __restrict__ mu, const float* __restrict__ va,
        ULL* __restrict__ qact1) {
    __shared__ float limg[30 * 30];   // limg[(x+1)*30 + (y+1)], borders zero
    int b = blockIdx.x, t = threadIdx.x;
    int wave = t >> 6, lane = t & 63;
    for (int i = t; i < 900; i += 448) limg[i] = 0.f;
    __syncthreads();
    const float* xb = x + (size_t)b * 784;
    for (int i = t; i < 784; i += 448) {
        int y = i / 28, xx = i - y * 28;
        limg[(xx + 1) * 30 + (y + 1)] = xb[i];   // transposed store
    }
    float w[9];
    #pragma unroll
    for (int k = 0; k < 9; ++k) w[k] = sgn1[lane * 9 + k];
    double iv = (double)g[lane] / sqrt((double)va[lane] + 1e-5);
    double cd = (double)be[lane] - (double)mu[lane] * iv;
    double bd = (double)b1[lane];
    __syncthreads();

    #pragma unroll
    for (int rr = 0; rr < 2; ++rr) {
        int py = wave + rr * 7;           // pool row 0..13
        const float* base = &limg[2 * py];  // col c at base[c*30 + r]
        #pragma unroll
        for (int px = 0; px < 14; ++px) {
            float a00 = 0.f, a01 = 0.f, a10 = 0.f, a11 = 0.f;
            #pragma unroll
            for (int ky = 0; ky < 3; ++ky) {
                #pragma unroll
                for (int kx = 0; kx < 3; ++kx) {
                    float sv = w[ky * 3 + kx];
                    a00 = fmaf(base[(2 * px + kx)     * 30 + ky],     sv, a00);
                    a01 = fmaf(base[(2 * px + kx + 1) * 30 + ky],     sv, a01);
                    a10 = fmaf(base[(2 * px + kx)     * 30 + ky + 1], sv, a10);
                    a11 = fmaf(base[(2 * px + kx + 1) * 30 + ky + 1], sv, a11);
                }
            }
            float m = fmaxf(fmaxf(a00, a01), fmaxf(a10, a11));
            double v  = (double)m + bd;
            double tt = v * iv + cd;
            ULL word = __ballot(tt >= 0.0);
            if (lane == 0) qact1[(size_t)b * 196 + py * 14 + px] = word;
        }
    }
}

// ---------------- k2 v3: conv2 + maxpool + bn2 + binarize -> qact2 bits ----------------
// one block per sample, 7 waves; wave = pool row; lane = out channel.
// px loop FULLY UNROLLED (immediate LDS offsets, compile-time corr class);
// BN+bias+binarize decision via EXACT precomputed integer threshold (monotone in m).
__global__ __launch_bounds__(448, 4) void k2_conv2(const ULL* __restrict__ qact1,
        const ULL* __restrict__ wb2, const float* __restrict__ b2,
        const float* __restrict__ g, const float* __restrict__ be,
        const float* __restrict__ mu, const float* __restrict__ va,
        ULL* __restrict__ qact2) {
    __shared__ ULL ap[16][16];
    int b = blockIdx.x, t = threadIdx.x;
    int pr = t >> 6, lane = t & 63;          // pr = pool row 0..6
    if (t < 256) ((ULL*)ap)[t] = 0ULL;
    __syncthreads();
    if (t < 196) ap[1 + t / 14][1 + t % 14] = qact1[(size_t)b * 196 + t];

    ULL wk[9];
    #pragma unroll
    for (int k = 0; k < 9; ++k) wk[k] = wb2[lane * 9 + k];
    int pw[9];
    #pragma unroll
    for (int k = 0; k < 9; ++k) pw[k] = 64 - 2 * (int)__popcll(wk[k]);

    // exact integer threshold for ((double)m + bias) * iv + cc >= 0, m in [-576,576]
    double iv   = (double)g[lane] / sqrt((double)va[lane] + 1e-5);
    double cc   = (double)be[lane] - (double)mu[lane] * iv;
    double bias = (double)b2[lane];
    int am, thr;
    if (iv > 0.0) {
        double t0 = -cc / iv - bias;
        int c = (t0 < -590.0) ? -590 : (t0 > 590.0 ? 590 : (int)floor(t0) - 2);
        if (c < -590) c = -590;
        while (c <= 590 && !(((double)c + bias) * iv + cc >= 0.0)) ++c;
        am = 1; thr = c;                     // pred: m >= thr
    } else if (iv < 0.0) {
        double t0 = -cc / iv - bias;
        int c = (t0 > 590.0) ? 590 : (t0 < -590.0 ? -590 : (int)ceil(t0) + 2);
        if (c > 590) c = 590;
        while (c >= -590 && !(((double)c + bias) * iv + cc >= 0.0)) --c;
        am = -1; thr = c;                    // pred: m <= thr  <=>  -m >= -thr
    } else {
        am = 1; thr = (cc >= 0.0) ? -1000000 : 1000000;
    }
    int athr = am * thr;

    // padding corrections: corr[j][cls], j = conv-row within pool pair, cls 0=L,1=M,2=R
    int corr[2][3];
    #pragma unroll
    for (int j = 0; j < 2; ++j) {
        bool tpad = (pr == 0 && j == 0);
        bool bpad = (pr == 6 && j == 1);
        #pragma unroll
        for (int cls = 0; cls < 3; ++cls) {
            int cacc = 0;
            #pragma unroll
            for (int r = 0; r < 3; ++r) {
                #pragma unroll
                for (int k = 0; k < 3; ++k) {
                    bool pad = (r == 0 && tpad) || (r == 2 && bpad) ||
                               (k == 0 && cls == 0) || (k == 2 && cls == 2);
                    if (pad) cacc += pw[r * 3 + k];
                }
            }
            corr[j][cls] = cacc;
        }
    }
    __syncthreads();

    const ULL* aprow = &ap[2 * pr][0];       // wave-uniform base; rows 2pr..2pr+3
    #pragma unroll
    for (int px = 0; px < 7; ++px) {
        int s00 = 0, s01 = 0, s10 = 0, s11 = 0;
        #pragma unroll
        for (int r = 0; r < 3; ++r) {
            #pragma unroll
            for (int k = 0; k < 3; ++k) {
                ULL w = wk[r * 3 + k];
                s00 += (int)__popcll(aprow[ r      * 16 + 2 * px + k    ] ^ w);
                s01 += (int)__popcll(aprow[ r      * 16 + 2 * px + k + 1] ^ w);
                s10 += (int)__popcll(aprow[(r + 1) * 16 + 2 * px + k    ] ^ w);
                s11 += (int)__popcll(aprow[(r + 1) * 16 + 2 * px + k + 1] ^ w);
            }
        }
        const int clsL = (px == 0) ? 0 : 1, clsR = (px == 6) ? 2 : 1;
        int d00 = 576 - 2 * s00 - corr[0][clsL];
        int d01 = 576 - 2 * s01 - corr[0][clsR];
        int d10 = 576 - 2 * s10 - corr[1][clsL];
        int d11 = 576 - 2 * s11 - corr[1][clsR];
        int m = max(max(d00, d01), max(d10, d11));
        ULL word = __ballot(am * m >= athr);
        if (lane == 0) qact2[(size_t)b * 49 + pr * 7 + px] = word;
    }
}

// ---------------- k3: fc1 + bn3 + binarize -> hbits ----------------
// block = 16 samples x 4 n-groups (wave = 64 outputs), weights reused 16x from L2
__global__ __launch_bounds__(256) void k3_fc1(const ULL* __restrict__ qact2,
        const ULL* __restrict__ wbT, const float* __restrict__ fb,
        const float* __restrict__ g, const float* __restrict__ be,
        const float* __restrict__ mu, const float* __restrict__ va,
        ULL* __restrict__ hbits) {
    __shared__ ULL xs[784];   // 16 samples x 49 words
    int t = threadIdx.x, wave = t >> 6, lane = t & 63;
    int b0 = blockIdx.x * 16;
    int gidx = blockIdx.y * 4 + wave;   // 0..31
    int n = gidx * 64 + lane;
    for (int i = t; i < 784; i += 256) xs[i] = qact2[(size_t)b0 * 49 + i];
    double iv   = (double)g[n] / sqrt((double)va[n] + 1e-5);
    double cc   = (double)be[n] - (double)mu[n] * iv;
    double bias = (double)fb[n];
    __syncthreads();
    int acc[16];
    #pragma unroll
    for (int i = 0; i < 16; ++i) acc[i] = 0;
    for (int p = 0; p < 49; ++p) {
        ULL w = wbT[p * 2048 + n];
        #pragma unroll
        for (int i = 0; i < 16; ++i)
            acc[i] += (int)__popcll(xs[i * 49 + p] ^ w);
    }
    #pragma unroll
    for (int i = 0; i < 16; ++i) {
        int dot = 3136 - 2 * acc[i];
        double tt = ((double)dot + bias) * iv + cc;
        ULL word = __ballot(tt >= 0.0);
        if (lane == 0) hbits[(size_t)(b0 + i) * 32 + gidx] = word;
    }
}

// ---------------- k4: fc2 + scale ----------------
__global__ __launch_bounds__(256) void k4_fc2(const ULL* __restrict__ hbits,
        const ULL* __restrict__ wbf2, const float* __restrict__ b2,
        const float* __restrict__ scale, float* __restrict__ out, int total) {
    int gid = blockIdx.x * 256 + threadIdx.x;
    if (gid >= total) return;
    int b = gid / 10, n = gid - b * 10;
    const ULL* h = hbits + (size_t)b * 32;
    const ULL* w = wbf2 + n * 32;
    int acc = 0;
    #pragma unroll
    for (int k = 0; k < 32; ++k) acc += (int)__popcll(h[k] ^ w[k]);
    int dot = 2048 - 2 * acc;
    double v = ((double)dot + (double)b2[n]) * (double)scale[0];
    out[gid] = (float)v;
}

// ---------------- launch ----------------
extern "C" void kernel_launch(void* const* d_in, const int* in_sizes, int n_in,
                              void* d_out, int out_size, void* d_ws, size_t ws_size,
                              hipStream_t stream) {
    const float* x      = (const float*)d_in[0];
    const float* w1     = (const float*)d_in[1];
    const float* b1     = (const float*)d_in[2];
    const float* w2     = (const float*)d_in[3];
    const float* b2     = (const float*)d_in[4];
    const float* fc1w   = (const float*)d_in[5];
    const float* fc1b   = (const float*)d_in[6];
    const float* fc2w   = (const float*)d_in[7];
    const float* fc2b   = (const float*)d_in[8];
    const float* g1 = (const float*)d_in[9],  *be1 = (const float*)d_in[10],
               *mu1 = (const float*)d_in[11], *va1 = (const float*)d_in[12];
    const float* g2 = (const float*)d_in[13], *be2 = (const float*)d_in[14],
               *mu2 = (const float*)d_in[15], *va2 = (const float*)d_in[16];
    const float* g3 = (const float*)d_in[17], *be3 = (const float*)d_in[18],
               *mu3 = (const float*)d_in[19], *va3 = (const float*)d_in[20];
    const float* scale = (const float*)d_in[21];
    float* out = (float*)d_out;

    int B = in_sizes[0] / 784;   // 4096

    // workspace layout (8B aligned)
    char* ws = (char*)d_ws;
    ULL* qact1 = (ULL*)(ws);                              // B*196 words
    ULL* qact2 = (ULL*)(ws + (size_t)B * 196 * 8);        // B*49 words
    ULL* hbits = (ULL*)(ws + (size_t)B * 245 * 8);        // B*32 words
    char* wsw  = ws + (size_t)B * 277 * 8;
    ULL* wb2   = (ULL*)(wsw);                             // 576 words
    ULL* wbT   = (ULL*)(wsw + 576 * 8);                   // 49*2048 words
    ULL* wbf2  = (ULL*)(wsw + 576 * 8 + 49 * 2048 * 8);   // 320 words
    float* sgn1 = (float*)(wsw + 576 * 8 + 49 * 2048 * 8 + 320 * 8); // 576 floats

    prep_small<<<227, 256, 0, stream>>>(w1, w2, fc2w, sgn1, wb2, wbf2);
    prep_pack_fc1<<<512, 256, 0, stream>>>(fc1w, wbT);   // 512 blocks x 4 rows = 2048

    k1_conv1<<<B, 448, 0, stream>>>(x, sgn1, b1, g1, be1, mu1, va1, qact1);
    k2_conv2<<<B, 448, 0, stream>>>(qact1, wb2, b2, g2, be2, mu2, va2, qact2);
    k3_fc1<<<dim3(B / 16, 8), 256, 0, stream>>>(qact2, wbT, fc1b, g3, be3, mu3, va3, hbits);
    int total = B * 10;
    k4_fc2<<<(total + 255) / 256, 256, 0, stream>>>(hbits, wbf2, fc2b, scale, out, total);
}

// Round 10
// 306.341 us; speedup vs baseline: 1.0258x; 1.0258x over previous
//
#include <hip/hip_runtime.h>
#include <stdint.h>

typedef unsigned long long ULL;

// ---------------- prep: conv1 signs + conv2/fc2 bit-packs in ONE kernel ----------------
// waves 0..575: wb2[co*9+tap] bit ci = sign(w2[co][ci][tap])
// waves 576..895: wbf2[n*32+k] bit j = sign(fc2w[n][k*64+j])
// waves 896..904: sgn1 (576 floats +-1)
__global__ __launch_bounds__(256) void prep_small(const float* __restrict__ w1,
        const float* __restrict__ w2, const float* __restrict__ fc2w,
        float* __restrict__ sgn1, ULL* __restrict__ wb2, ULL* __restrict__ wbf2) {
    int wave = threadIdx.x >> 6, lane = threadIdx.x & 63;
    int W = blockIdx.x * 4 + wave;
    if (W < 576) {
        int co = W / 9, tap = W - co * 9;
        ULL wd = __ballot(w2[(co * 64 + lane) * 9 + tap] >= 0.f);
        if (lane == 0) wb2[W] = wd;
    } else if (W < 896) {
        int idx = W - 576;
        int n = idx >> 5, k = idx & 31;
        ULL wd = __ballot(fc2w[n * 2048 + k * 64 + lane] >= 0.f);
        if (lane == 0) wbf2[idx] = wd;
    } else if (W < 905) {
        int i = (W - 896) * 64 + lane;
        if (i < 576) sgn1[i] = (w1[i] >= 0.f) ? 1.f : -1.f;
    }
}

// fc1 weights transposed: wbT[p*2048 + n] bit c = sign(fc1w[n][c*49+p])
// stage 4 contiguous rows in LDS coalesced, ballot from LDS. GRID = 512 blocks.
__global__ __launch_bounds__(256) void prep_pack_fc1(const float* __restrict__ fc1w,
                                                     ULL* __restrict__ wbT) {
    __shared__ float rows[4 * 3136];
    int t = threadIdx.x;
    const float* src = fc1w + (size_t)blockIdx.x * 4 * 3136;
    for (int i = t; i < 4 * 3136; i += 256) rows[i] = src[i];
    __syncthreads();
    int wave = t >> 6, lane = t & 63;
    int n = blockIdx.x * 4 + wave;
    const float* r = rows + wave * 3136 + lane * 49;   // stride 49 % 32 = 17 -> 2-way, free
    for (int p = 0; p < 49; ++p) {
        ULL wd = __ballot(r[p] >= 0.f);
        if (lane == 0) wbT[p * 2048 + n] = wd;
    }
}

// ---------------- k1 v3: conv1 + maxpool + bn1 + binarize -> qact1 bits ----------------
// one block per sample, 7 waves; lane = output channel (weights + BN consts in registers);
// wave = pool rows w and w+7; image column-major zero-padded 30x30 in LDS;
// px loop FULLY UNROLLED -> immediate LDS offsets, no slide movs.
__global__ __launch_bounds__(448, 4) void k1_conv1(const float* __restrict__ x,
        const float* __restrict__ sgn1, const float* __restrict__ b1,
        const float* __restrict__ g, const float* __restrict__ be,
        const float* __restrict__ mu, const float* __restrict__ va,
        ULL* __restrict__ qact1) {
    __shared__ float limg[30 * 30];   // limg[(x+1)*30 + (y+1)], borders zero
    int b = blockIdx.x, t = threadIdx.x;
    int wave = t >> 6, lane = t & 63;
    for (int i = t; i < 900; i += 448) limg[i] = 0.f;
    __syncthreads();
    const float* xb = x + (size_t)b * 784;
    for (int i = t; i < 784; i += 448) {
        int y = i / 28, xx = i - y * 28;
        limg[(xx + 1) * 30 + (y + 1)] = xb[i];   // transposed store
    }
    float w[9];
    #pragma unroll
    for (int k = 0; k < 9; ++k) w[k] = sgn1[lane * 9 + k];
    double iv = (double)g[lane] / sqrt((double)va[lane] + 1e-5);
    double cd = (double)be[lane] - (double)mu[lane] * iv;
    double bd = (double)b1[lane];
    __syncthreads();

    #pragma unroll
    for (int rr = 0; rr < 2; ++rr) {
        int py = wave + rr * 7;           // pool row 0..13
        const float* base = &limg[2 * py];  // col c at base[c*30 + r]
        #pragma unroll
        for (int px = 0; px < 14; ++px) {
            float a00 = 0.f, a01 = 0.f, a10 = 0.f, a11 = 0.f;
            #pragma unroll
            for (int ky = 0; ky < 3; ++ky) {
                #pragma unroll
                for (int kx = 0; kx < 3; ++kx) {
                    float sv = w[ky * 3 + kx];
                    a00 = fmaf(base[(2 * px + kx)     * 30 + ky],     sv, a00);
                    a01 = fmaf(base[(2 * px + kx + 1) * 30 + ky],     sv, a01);
                    a10 = fmaf(base[(2 * px + kx)     * 30 + ky + 1], sv, a10);
                    a11 = fmaf(base[(2 * px + kx + 1) * 30 + ky + 1], sv, a11);
                }
            }
            float m = fmaxf(fmaxf(a00, a01), fmaxf(a10, a11));
            double v  = (double)m + bd;
            double tt = v * iv + cd;
            ULL word = __ballot(tt >= 0.0);
            if (lane == 0) qact1[(size_t)b * 196 + py * 14 + px] = word;
        }
    }
}

// ---------------- k2 v4: conv2 + maxpool + bn2 + binarize -> qact2 bits ----------------
// ONE WAVE per (sample, pool row); 256-thread blocks = 4 independent waves; NO LDS,
// NO barriers. 4x4 u64 window held in REGISTERS, fed by wave-uniform global loads
// (qact1 is L2-resident). Pads are zero registers; exact corr subtraction and exact
// integer-threshold binarize (identical math to the passing v3 -> absmax 0).
__global__ __launch_bounds__(256, 1) void k2_conv2(const ULL* __restrict__ qact1,
        const ULL* __restrict__ wb2, const float* __restrict__ b2,
        const float* __restrict__ g, const float* __restrict__ be,
        const float* __restrict__ mu, const float* __restrict__ va,
        ULL* __restrict__ qact2) {
    int lane = threadIdx.x & 63;
    int wid = blockIdx.x * 4 + (threadIdx.x >> 6);   // wave id
    int s = wid / 7, pr = wid - s * 7;               // sample, pool row 0..6

    // per-lane (= output channel) weights
    ULL wk[9];
    #pragma unroll
    for (int k = 0; k < 9; ++k) wk[k] = wb2[lane * 9 + k];
    int pw[9];
    #pragma unroll
    for (int k = 0; k < 9; ++k) pw[k] = 64 - 2 * (int)__popcll(wk[k]);

    // exact integer threshold for ((double)m + bias) * iv + cc >= 0, m in [-576,576]
    double iv   = (double)g[lane] / sqrt((double)va[lane] + 1e-5);
    double cc   = (double)be[lane] - (double)mu[lane] * iv;
    double bias = (double)b2[lane];
    int am, thr;
    if (iv > 0.0) {
        double t0 = -cc / iv - bias;
        int c = (t0 < -590.0) ? -590 : (t0 > 590.0 ? 590 : (int)floor(t0) - 2);
        if (c < -590) c = -590;
        while (c <= 590 && !(((double)c + bias) * iv + cc >= 0.0)) ++c;
        am = 1; thr = c;                     // pred: m >= thr
    } else if (iv < 0.0) {
        double t0 = -cc / iv - bias;
        int c = (t0 > 590.0) ? 590 : (t0 < -590.0 ? -590 : (int)ceil(t0) + 2);
        if (c > 590) c = 590;
        while (c >= -590 && !(((double)c + bias) * iv + cc >= 0.0)) --c;
        am = -1; thr = c;                    // pred: m <= thr  <=>  -m >= -thr
    } else {
        am = 1; thr = (cc >= 0.0) ? -1000000 : 1000000;
    }
    int athr = am * thr;

    // padding corrections: corr[j][cls], j = conv-row within pool pair, cls 0=L,1=M,2=R
    int corr[2][3];
    #pragma unroll
    for (int j = 0; j < 2; ++j) {
        bool tpad = (pr == 0 && j == 0);
        bool bpad = (pr == 6 && j == 1);
        #pragma unroll
        for (int cls = 0; cls < 3; ++cls) {
            int cacc = 0;
            #pragma unroll
            for (int r = 0; r < 3; ++r) {
                #pragma unroll
                for (int k = 0; k < 3; ++k) {
                    bool pad = (r == 0 && tpad) || (r == 2 && bpad) ||
                               (k == 0 && cls == 0) || (k == 2 && cls == 2);
                    if (pad) cacc += pw[r * 3 + k];
                }
            }
            corr[j][cls] = cacc;
        }
    }

    const ULL* base = qact1 + (size_t)s * 196;
    int r0 = 2 * pr;                 // window = image rows r0-1..r0+2 (pad outside 0..13)
    bool top = (pr > 0), bot = (pr < 6);

    // cw[slot][row]: slot k holds image col (2*px - 1 + k); col -1 / 14 are zero regs
    ULL cw[4][4];
    #pragma unroll
    for (int r = 0; r < 4; ++r) cw[0][r] = 0ULL;
    #pragma unroll
    for (int c = 0; c < 3; ++c) {
        cw[c + 1][0] = top ? base[(r0 - 1) * 14 + c] : 0ULL;
        cw[c + 1][1] = base[(r0    ) * 14 + c];
        cw[c + 1][2] = base[(r0 + 1) * 14 + c];
        cw[c + 1][3] = bot ? base[(r0 + 2) * 14 + c] : 0ULL;
    }

    #pragma unroll
    for (int px = 0; px < 7; ++px) {
        int s00 = 0, s01 = 0, s10 = 0, s11 = 0;
        #pragma unroll
        for (int ky = 0; ky < 3; ++ky) {
            #pragma unroll
            for (int kx = 0; kx < 3; ++kx) {
                ULL w = wk[ky * 3 + kx];
                s00 += (int)__popcll(cw[kx    ][ky    ] ^ w);
                s01 += (int)__popcll(cw[kx + 1][ky    ] ^ w);
                s10 += (int)__popcll(cw[kx    ][ky + 1] ^ w);
                s11 += (int)__popcll(cw[kx + 1][ky + 1] ^ w);
            }
        }
        const int clsL = (px == 0) ? 0 : 1, clsR = (px == 6) ? 2 : 1;
        int d00 = 576 - 2 * s00 - corr[0][clsL];
        int d01 = 576 - 2 * s01 - corr[0][clsR];
        int d10 = 576 - 2 * s10 - corr[1][clsL];
        int d11 = 576 - 2 * s11 - corr[1][clsR];
        int m = max(max(d00, d01), max(d10, d11));
        ULL word = __ballot(am * m >= athr);
        if (lane == 0) qact2[(size_t)s * 49 + pr * 7 + px] = word;
        if (px < 6) {   // slide window by one pool step (2 cols)
            #pragma unroll
            for (int r = 0; r < 4; ++r) { cw[0][r] = cw[2][r]; cw[1][r] = cw[3][r]; }
            #pragma unroll
            for (int c = 0; c < 2; ++c) {
                const int col = 2 * px + 3 + c;            // compile-time per unrolled px
                if (col <= 13) {
                    cw[2 + c][0] = top ? base[(r0 - 1) * 14 + col] : 0ULL;
                    cw[2 + c][1] = base[(r0    ) * 14 + col];
                    cw[2 + c][2] = base[(r0 + 1) * 14 + col];
                    cw[2 + c][3] = bot ? base[(r0 + 2) * 14 + col] : 0ULL;
                } else {
                    cw[2 + c][0] = 0ULL; cw[2 + c][1] = 0ULL;
                    cw[2 + c][2] = 0ULL; cw[2 + c][3] = 0ULL;
                }
            }
        }
    }
}

// ---------------- k3: fc1 + bn3 + binarize -> hbits ----------------
// block = 16 samples x 4 n-groups (wave = 64 outputs), weights reused 16x from L2
__global__ __launch_bounds__(256) void k3_fc1(const ULL* __restrict__ qact2,
        const ULL* __restrict__ wbT, const float* __restrict__ fb,
        const float* __restrict__ g, const float* __restrict__ be,
        const float* __restrict__ mu, const float* __restrict__ va,
        ULL* __restrict__ hbits) {
    __shared__ ULL xs[784];   // 16 samples x 49 words
    int t = threadIdx.x, wave = t >> 6, lane = t & 63;
    int b0 = blockIdx.x * 16;
    int gidx = blockIdx.y * 4 + wave;   // 0..31
    int n = gidx * 64 + lane;
    for (int i = t; i < 784; i += 256) xs[i] = qact2[(size_t)b0 * 49 + i];
    double iv   = (double)g[n] / sqrt((double)va[n] + 1e-5);
    double cc   = (double)be[n] - (double)mu[n] * iv;
    double bias = (double)fb[n];
    __syncthreads();
    int acc[16];
    #pragma unroll
    for (int i = 0; i < 16; ++i) acc[i] = 0;
    for (int p = 0; p < 49; ++p) {
        ULL w = wbT[p * 2048 + n];
        #pragma unroll
        for (int i = 0; i < 16; ++i)
            acc[i] += (int)__popcll(xs[i * 49 + p] ^ w);
    }
    #pragma unroll
    for (int i = 0; i < 16; ++i) {
        int dot = 3136 - 2 * acc[i];
        double tt = ((double)dot + bias) * iv + cc;
        ULL word = __ballot(tt >= 0.0);
        if (lane == 0) hbits[(size_t)(b0 + i) * 32 + gidx] = word;
    }
}

// ---------------- k4: fc2 + scale ----------------
__global__ __launch_bounds__(256) void k4_fc2(const ULL* __restrict__ hbits,
        const ULL* __restrict__ wbf2, const float* __restrict__ b2,
        const float* __restrict__ scale, float* __restrict__ out, int total) {
    int gid = blockIdx.x * 256 + threadIdx.x;
    if (gid >= total) return;
    int b = gid / 10, n = gid - b * 10;
    const ULL* h = hbits + (size_t)b * 32;
    const ULL* w = wbf2 + n * 32;
    int acc = 0;
    #pragma unroll
    for (int k = 0; k < 32; ++k) acc += (int)__popcll(h[k] ^ w[k]);
    int dot = 2048 - 2 * acc;
    double v = ((double)dot + (double)b2[n]) * (double)scale[0];
    out[gid] = (float)v;
}

// ---------------- launch ----------------
extern "C" void kernel_launch(void* const* d_in, const int* in_sizes, int n_in,
                              void* d_out, int out_size, void* d_ws, size_t ws_size,
                              hipStream_t stream) {
    const float* x      = (const float*)d_in[0];
    const float* w1     = (const float*)d_in[1];
    const float* b1     = (const float*)d_in[2];
    const float* w2     = (const float*)d_in[3];
    const float* b2     = (const float*)d_in[4];
    const float* fc1w   = (const float*)d_in[5];
    const float* fc1b   = (const float*)d_in[6];
    const float* fc2w   = (const float*)d_in[7];
    const float* fc2b   = (const float*)d_in[8];
    const float* g1 = (const float*)d_in[9],  *be1 = (const float*)d_in[10],
               *mu1 = (const float*)d_in[11], *va1 = (const float*)d_in[12];
    const float* g2 = (const float*)d_in[13], *be2 = (const float*)d_in[14],
               *mu2 = (const float*)d_in[15], *va2 = (const float*)d_in[16];
    const float* g3 = (const float*)d_in[17], *be3 = (const float*)d_in[18],
               *mu3 = (const float*)d_in[19], *va3 = (const float*)d_in[20];
    const float* scale = (const float*)d_in[21];
    float* out = (float*)d_out;

    int B = in_sizes[0] / 784;   // 4096

    // workspace layout (8B aligned)
    char* ws = (char*)d_ws;
    ULL* qact1 = (ULL*)(ws);                              // B*196 words
    ULL* qact2 = (ULL*)(ws + (size_t)B * 196 * 8);        // B*49 words
    ULL* hbits = (ULL*)(ws + (size_t)B * 245 * 8);        // B*32 words
    char* wsw  = ws + (size_t)B * 277 * 8;
    ULL* wb2   = (ULL*)(wsw);                             // 576 words
    ULL* wbT   = (ULL*)(wsw + 576 * 8);                   // 49*2048 words
    ULL* wbf2  = (ULL*)(wsw + 576 * 8 + 49 * 2048 * 8);   // 320 words
    float* sgn1 = (float*)(wsw + 576 * 8 + 49 * 2048 * 8 + 320 * 8); // 576 floats

    prep_small<<<227, 256, 0, stream>>>(w1, w2, fc2w, sgn1, wb2, wbf2);
    prep_pack_fc1<<<512, 256, 0, stream>>>(fc1w, wbT);   // 512 blocks x 4 rows = 2048

    k1_conv1<<<B, 448, 0, stream>>>(x, sgn1, b1, g1, be1, mu1, va1, qact1);
    k2_conv2<<<B * 7 / 4, 256, 0, stream>>>(qact1, wb2, b2, g2, be2, mu2, va2, qact2);
    k3_fc1<<<dim3(B / 16, 8), 256, 0, stream>>>(qact2, wbT, fc1b, g3, be3, mu3, va3, hbits);
    int total = B * 10;
    k4_fc2<<<(total + 255) / 256, 256, 0, stream>>>(hbits, wbf2, fc2b, scale, out, total);
}

// Round 11
// 303.158 us; speedup vs baseline: 1.0366x; 1.0105x over previous
//
#include <hip/hip_runtime.h>
#include <stdint.h>

typedef unsigned long long ULL;

// ---------------- prep: conv1 signs + conv2/fc2 bit-packs in ONE kernel ----------------
__global__ __launch_bounds__(256) void prep_small(const float* __restrict__ w1,
        const float* __restrict__ w2, const float* __restrict__ fc2w,
        float* __restrict__ sgn1, ULL* __restrict__ wb2, ULL* __restrict__ wbf2) {
    int wave = threadIdx.x >> 6, lane = threadIdx.x & 63;
    int W = blockIdx.x * 4 + wave;
    if (W < 576) {
        int co = W / 9, tap = W - co * 9;
        ULL wd = __ballot(w2[(co * 64 + lane) * 9 + tap] >= 0.f);
        if (lane == 0) wb2[W] = wd;
    } else if (W < 896) {
        int idx = W - 576;
        int n = idx >> 5, k = idx & 31;
        ULL wd = __ballot(fc2w[n * 2048 + k * 64 + lane] >= 0.f);
        if (lane == 0) wbf2[idx] = wd;
    } else if (W < 905) {
        int i = (W - 896) * 64 + lane;
        if (i < 576) sgn1[i] = (w1[i] >= 0.f) ? 1.f : -1.f;
    }
}

// fc1 weights transposed: wbT[p*2048 + n] bit c = sign(fc1w[n][c*49+p]); GRID = 512.
__global__ __launch_bounds__(256) void prep_pack_fc1(const float* __restrict__ fc1w,
                                                     ULL* __restrict__ wbT) {
    __shared__ float rows[4 * 3136];
    int t = threadIdx.x;
    const float* src = fc1w + (size_t)blockIdx.x * 4 * 3136;
    for (int i = t; i < 4 * 3136; i += 256) rows[i] = src[i];
    __syncthreads();
    int wave = t >> 6, lane = t & 63;
    int n = blockIdx.x * 4 + wave;
    const float* r = rows + wave * 3136 + lane * 49;
    for (int p = 0; p < 49; ++p) {
        ULL wd = __ballot(r[p] >= 0.f);
        if (lane == 0) wbT[p * 2048 + n] = wd;
    }
}

// ---------------- k1 v3: conv1 + maxpool + bn1 + binarize -> qact1 bits ----------------
__global__ __launch_bounds__(448, 4) void k1_conv1(const float* __restrict__ x,
        const float* __restrict__ sgn1, const float* __restrict__ b1,
        const float* __restrict__ g, const float* __restrict__ be,
        const float* __restrict__ mu, const float* __restrict__ va,
        ULL* __restrict__ qact1) {
    __shared__ float limg[30 * 30];   // limg[(x+1)*30 + (y+1)], borders zero
    int b = blockIdx.x, t = threadIdx.x;
    int wave = t >> 6, lane = t & 63;
    for (int i = t; i < 900; i += 448) limg[i] = 0.f;
    __syncthreads();
    const float* xb = x + (size_t)b * 784;
    for (int i = t; i < 784; i += 448) {
        int y = i / 28, xx = i - y * 28;
        limg[(xx + 1) * 30 + (y + 1)] = xb[i];   // transposed store
    }
    float w[9];
    #pragma unroll
    for (int k = 0; k < 9; ++k) w[k] = sgn1[lane * 9 + k];
    double iv = (double)g[lane] / sqrt((double)va[lane] + 1e-5);
    double cd = (double)be[lane] - (double)mu[lane] * iv;
    double bd = (double)b1[lane];
    __syncthreads();

    #pragma unroll
    for (int rr = 0; rr < 2; ++rr) {
        int py = wave + rr * 7;           // pool row 0..13
        const float* base = &limg[2 * py];
        #pragma unroll
        for (int px = 0; px < 14; ++px) {
            float a00 = 0.f, a01 = 0.f, a10 = 0.f, a11 = 0.f;
            #pragma unroll
            for (int ky = 0; ky < 3; ++ky) {
                #pragma unroll
                for (int kx = 0; kx < 3; ++kx) {
                    float sv = w[ky * 3 + kx];
                    a00 = fmaf(base[(2 * px + kx)     * 30 + ky],     sv, a00);
                    a01 = fmaf(base[(2 * px + kx + 1) * 30 + ky],     sv, a01);
                    a10 = fmaf(base[(2 * px + kx)     * 30 + ky + 1], sv, a10);
                    a11 = fmaf(base[(2 * px + kx + 1) * 30 + ky + 1], sv, a11);
                }
            }
            float m = fmaxf(fmaxf(a00, a01), fmaxf(a10, a11));
            double v  = (double)m + bd;
            double tt = v * iv + cd;
            ULL word = __ballot(tt >= 0.0);
            if (lane == 0) qact1[(size_t)b * 196 + py * 14 + px] = word;
        }
    }
}

// ---------------- k2 v5: conv2 + maxpool + bn2 + binarize -> qact2 bits ----------------
// ONE WAVE per SAMPLE (prologue amortized over 49 positions); no LDS, no barriers.
// Register window with COMPILE-TIME SLOT ROTATION: logical col c -> slot (c+1)&3,
// px fully unrolled so all indices fold (zero slide movs). Rows clamped + masked
// branchless. Identical pw/corr/threshold math as the passing v4 -> absmax 0.
__global__ __launch_bounds__(256, 1) void k2_conv2(const ULL* __restrict__ qact1,
        const ULL* __restrict__ wb2, const float* __restrict__ b2,
        const float* __restrict__ g, const float* __restrict__ be,
        const float* __restrict__ mu, const float* __restrict__ va,
        ULL* __restrict__ qact2) {
    int lane = threadIdx.x & 63;
    int s = blockIdx.x * 4 + (threadIdx.x >> 6);   // sample id

    // per-lane (= output channel) weights
    ULL wk[9];
    #pragma unroll
    for (int k = 0; k < 9; ++k) wk[k] = wb2[lane * 9 + k];
    int pw[9];
    #pragma unroll
    for (int k = 0; k < 9; ++k) pw[k] = 64 - 2 * (int)__popcll(wk[k]);

    // exact integer threshold for ((double)m + bias) * iv + cc >= 0, m in [-576,576]
    double iv   = (double)g[lane] / sqrt((double)va[lane] + 1e-5);
    double cc   = (double)be[lane] - (double)mu[lane] * iv;
    double bias = (double)b2[lane];
    int am, thr;
    if (iv > 0.0) {
        double t0 = -cc / iv - bias;
        int c = (t0 < -590.0) ? -590 : (t0 > 590.0 ? 590 : (int)floor(t0) - 2);
        if (c < -590) c = -590;
        while (c <= 590 && !(((double)c + bias) * iv + cc >= 0.0)) ++c;
        am = 1; thr = c;                     // pred: m >= thr
    } else if (iv < 0.0) {
        double t0 = -cc / iv - bias;
        int c = (t0 > 590.0) ? 590 : (t0 < -590.0 ? -590 : (int)ceil(t0) + 2);
        if (c > 590) c = 590;
        while (c >= -590 && !(((double)c + bias) * iv + cc >= 0.0)) --c;
        am = -1; thr = c;                    // pred: m <= thr  <=>  -m >= -thr
    } else {
        am = 1; thr = (cc >= 0.0) ? -1000000 : 1000000;
    }
    int athr = am * thr;

    // corr building blocks (union-of-padded-taps sums; corners subtracted once)
    int cLs = pw[0] + pw[3] + pw[6], cRs = pw[2] + pw[5] + pw[8];
    int rT  = pw[0] + pw[1] + pw[2], rB  = pw[6] + pw[7] + pw[8];
    int tL = cLs + rT - pw[0], tM = rT, tR = cRs + rT - pw[2];
    int bL = cLs + rB - pw[6], bM = rB, bR = cRs + rB - pw[8];

    const ULL* base = qact1 + (size_t)s * 196;
    ULL cw[4][4];                            // [slot][window row]; all indices compile-time

    #pragma unroll 1
    for (int pr = 0; pr < 7; ++pr) {
        int r0 = 2 * pr;
        bool tpad = (pr == 0), bpad = (pr == 6);
        const ULL* rA = base + (tpad ? 0 : (r0 - 1) * 14);   // clamped (masked below)
        const ULL* rB_ = base + r0 * 14;
        const ULL* rC = base + (r0 + 1) * 14;
        const ULL* rD = base + (bpad ? 0 : (r0 + 2) * 14);
        ULL mT = tpad ? 0ULL : ~0ULL;
        ULL mB = bpad ? 0ULL : ~0ULL;
        // per-row corr selections (j=0 -> s00/s01, j=1 -> s10/s11)
        int c00 = tpad ? tL : cLs, c01 = tpad ? tM : 0, c02 = tpad ? tR : cRs;
        int c10 = bpad ? bL : cLs, c11 = bpad ? bM : 0, c12 = bpad ? bR : cRs;

        // init: col -1 zeros in slot 0; cols 0..2 in slots 1..3
        #pragma unroll
        for (int r = 0; r < 4; ++r) cw[0][r] = 0ULL;
        #pragma unroll
        for (int c = 0; c < 3; ++c) {
            cw[c + 1][0] = rA[c] & mT;
            cw[c + 1][1] = rB_[c];
            cw[c + 1][2] = rC[c];
            cw[c + 1][3] = rD[c] & mB;
        }

        #pragma unroll
        for (int px = 0; px < 7; ++px) {
            int s00 = 0, s01 = 0, s10 = 0, s11 = 0;
            #pragma unroll
            for (int ky = 0; ky < 3; ++ky) {
                #pragma unroll
                for (int kx = 0; kx < 3; ++kx) {
                    ULL w = wk[ky * 3 + kx];
                    s00 += (int)__popcll(cw[(2 * px + kx)     & 3][ky    ] ^ w);
                    s01 += (int)__popcll(cw[(2 * px + kx + 1) & 3][ky    ] ^ w);
                    s10 += (int)__popcll(cw[(2 * px + kx)     & 3][ky + 1] ^ w);
                    s11 += (int)__popcll(cw[(2 * px + kx + 1) & 3][ky + 1] ^ w);
                }
            }
            int d00 = 576 - 2 * s00 - ((px == 0) ? c00 : c01);
            int d01 = 576 - 2 * s01 - ((px == 6) ? c02 : c01);
            int d10 = 576 - 2 * s10 - ((px == 0) ? c10 : c11);
            int d11 = 576 - 2 * s11 - ((px == 6) ? c12 : c11);
            int m = max(max(d00, d01), max(d10, d11));
            ULL word = __ballot(am * m >= athr);
            if (lane == 0) qact2[(size_t)s * 49 + pr * 7 + px] = word;

            if (px < 6) {   // load next two logical cols into their rotated slots
                const int n1 = 2 * px + 3, n2 = 2 * px + 4;   // n1 <= 13 always
                cw[(n1 + 1) & 3][0] = rA[n1] & mT;
                cw[(n1 + 1) & 3][1] = rB_[n1];
                cw[(n1 + 1) & 3][2] = rC[n1];
                cw[(n1 + 1) & 3][3] = rD[n1] & mB;
                if (n2 <= 13) {
                    cw[(n2 + 1) & 3][0] = rA[n2] & mT;
                    cw[(n2 + 1) & 3][1] = rB_[n2];
                    cw[(n2 + 1) & 3][2] = rC[n2];
                    cw[(n2 + 1) & 3][3] = rD[n2] & mB;
                } else {
                    #pragma unroll
                    for (int r = 0; r < 4; ++r) cw[(n2 + 1) & 3][r] = 0ULL;
                }
            }
        }
    }
}

// ---------------- k3: fc1 + bn3 + binarize -> hbits ----------------
__global__ __launch_bounds__(256) void k3_fc1(const ULL* __restrict__ qact2,
        const ULL* __restrict__ wbT, const float* __restrict__ fb,
        const float* __restrict__ g, const float* __restrict__ be,
        const float* __restrict__ mu, const float* __restrict__ va,
        ULL* __restrict__ hbits) {
    __shared__ ULL xs[784];   // 16 samples x 49 words
    int t = threadIdx.x, wave = t >> 6, lane = t & 63;
    int b0 = blockIdx.x * 16;
    int gidx = blockIdx.y * 4 + wave;   // 0..31
    int n = gidx * 64 + lane;
    for (int i = t; i < 784; i += 256) xs[i] = qact2[(size_t)b0 * 49 + i];
    double iv   = (double)g[n] / sqrt((double)va[n] + 1e-5);
    double cc   = (double)be[n] - (double)mu[n] * iv;
    double bias = (double)fb[n];
    __syncthreads();
    int acc[16];
    #pragma unroll
    for (int i = 0; i < 16; ++i) acc[i] = 0;
    for (int p = 0; p < 49; ++p) {
        ULL w = wbT[p * 2048 + n];
        #pragma unroll
        for (int i = 0; i < 16; ++i)
            acc[i] += (int)__popcll(xs[i * 49 + p] ^ w);
    }
    #pragma unroll
    for (int i = 0; i < 16; ++i) {
        int dot = 3136 - 2 * acc[i];
        double tt = ((double)dot + bias) * iv + cc;
        ULL word = __ballot(tt >= 0.0);
        if (lane == 0) hbits[(size_t)(b0 + i) * 32 + gidx] = word;
    }
}

// ---------------- k4: fc2 + scale ----------------
__global__ __launch_bounds__(256) void k4_fc2(const ULL* __restrict__ hbits,
        const ULL* __restrict__ wbf2, const float* __restrict__ b2,
        const float* __restrict__ scale, float* __restrict__ out, int total) {
    int gid = blockIdx.x * 256 + threadIdx.x;
    if (gid >= total) return;
    int b = gid / 10, n = gid - b * 10;
    const ULL* h = hbits + (size_t)b * 32;
    const ULL* w = wbf2 + n * 32;
    int acc = 0;
    #pragma unroll
    for (int k = 0; k < 32; ++k) acc += (int)__popcll(h[k] ^ w[k]);
    int dot = 2048 - 2 * acc;
    double v = ((double)dot + (double)b2[n]) * (double)scale[0];
    out[gid] = (float)v;
}

// ---------------- launch ----------------
extern "C" void kernel_launch(void* const* d_in, const int* in_sizes, int n_in,
                              void* d_out, int out_size, void* d_ws, size_t ws_size,
                              hipStream_t stream) {
    const float* x      = (const float*)d_in[0];
    const float* w1     = (const float*)d_in[1];
    const float* b1     = (const float*)d_in[2];
    const float* w2     = (const float*)d_in[3];
    const float* b2     = (const float*)d_in[4];
    const float* fc1w   = (const float*)d_in[5];
    const float* fc1b   = (const float*)d_in[6];
    const float* fc2w   = (const float*)d_in[7];
    const float* fc2b   = (const float*)d_in[8];
    const float* g1 = (const float*)d_in[9],  *be1 = (const float*)d_in[10],
               *mu1 = (const float*)d_in[11], *va1 = (const float*)d_in[12];
    const float* g2 = (const float*)d_in[13], *be2 = (const float*)d_in[14],
               *mu2 = (const float*)d_in[15], *va2 = (const float*)d_in[16];
    const float* g3 = (const float*)d_in[17], *be3 = (const float*)d_in[18],
               *mu3 = (const float*)d_in[19], *va3 = (const float*)d_in[20];
    const float* scale = (const float*)d_in[21];
    float* out = (float*)d_out;

    int B = in_sizes[0] / 784;   // 4096

    // workspace layout (8B aligned)
    char* ws = (char*)d_ws;
    ULL* qact1 = (ULL*)(ws);                              // B*196 words
    ULL* qact2 = (ULL*)(ws + (size_t)B * 196 * 8);        // B*49 words
    ULL* hbits = (ULL*)(ws + (size_t)B * 245 * 8);        // B*32 words
    char* wsw  = ws + (size_t)B * 277 * 8;
    ULL* wb2   = (ULL*)(wsw);                             // 576 words
    ULL* wbT   = (ULL*)(wsw + 576 * 8);                   // 49*2048 words
    ULL* wbf2  = (ULL*)(wsw + 576 * 8 + 49 * 2048 * 8);   // 320 words
    float* sgn1 = (float*)(wsw + 576 * 8 + 49 * 2048 * 8 + 320 * 8); // 576 floats

    prep_small<<<227, 256, 0, stream>>>(w1, w2, fc2w, sgn1, wb2, wbf2);
    prep_pack_fc1<<<512, 256, 0, stream>>>(fc1w, wbT);   // 512 blocks x 4 rows = 2048

    k1_conv1<<<B, 448, 0, stream>>>(x, sgn1, b1, g1, be1, mu1, va1, qact1);
    k2_conv2<<<B / 4, 256, 0, stream>>>(qact1, wb2, b2, g2, be2, mu2, va2, qact2);
    k3_fc1<<<dim3(B / 16, 8), 256, 0, stream>>>(qact2, wbT, fc1b, g3, be3, mu3, va3, hbits);
    int total = B * 10;
    k4_fc2<<<(total + 255) / 256, 256, 0, stream>>>(hbits, wbf2, fc2b, scale, out, total);
}

// Round 12
// 299.274 us; speedup vs baseline: 1.0500x; 1.0130x over previous
//
#include <hip/hip_runtime.h>
#include <stdint.h>
#include <math.h>

typedef unsigned long long ULL;

// ---------------- prep: conv1 signs + conv2/fc2 bit-packs in ONE kernel ----------------
__global__ __launch_bounds__(256) void prep_small(const float* __restrict__ w1,
        const float* __restrict__ w2, const float* __restrict__ fc2w,
        float* __restrict__ sgn1, ULL* __restrict__ wb2, ULL* __restrict__ wbf2) {
    int wave = threadIdx.x >> 6, lane = threadIdx.x & 63;
    int W = blockIdx.x * 4 + wave;
    if (W < 576) {
        int co = W / 9, tap = W - co * 9;
        ULL wd = __ballot(w2[(co * 64 + lane) * 9 + tap] >= 0.f);
        if (lane == 0) wb2[W] = wd;
    } else if (W < 896) {
        int idx = W - 576;
        int n = idx >> 5, k = idx & 31;
        ULL wd = __ballot(fc2w[n * 2048 + k * 64 + lane] >= 0.f);
        if (lane == 0) wbf2[idx] = wd;
    } else if (W < 905) {
        int i = (W - 896) * 64 + lane;
        if (i < 576) sgn1[i] = (w1[i] >= 0.f) ? 1.f : -1.f;
    }
}

// fc1 weights transposed: wbT[p*2048 + n] bit c = sign(fc1w[n][c*49+p]); GRID = 512.
__global__ __launch_bounds__(256) void prep_pack_fc1(const float* __restrict__ fc1w,
                                                     ULL* __restrict__ wbT) {
    __shared__ float rows[4 * 3136];
    int t = threadIdx.x;
    const float* src = fc1w + (size_t)blockIdx.x * 4 * 3136;
    for (int i = t; i < 4 * 3136; i += 256) rows[i] = src[i];
    __syncthreads();
    int wave = t >> 6, lane = t & 63;
    int n = blockIdx.x * 4 + wave;
    const float* r = rows + wave * 3136 + lane * 49;
    for (int p = 0; p < 49; ++p) {
        ULL wd = __ballot(r[p] >= 0.f);
        if (lane == 0) wbT[p * 2048 + n] = wd;
    }
}

// ---------------- k1 v4: conv1 + maxpool + bn1 + binarize -> qact1 bits ----------------
// 448 threads; lane = output channel; wave = pool rows w and w+7; image column-major
// zero-padded 30x30 in LDS; px fully unrolled. BN+binarize decision via EXACT per-lane
// FLOAT threshold (monotone nextafterf walk from the f64 root): inner loop = mul+cmp.
__global__ __launch_bounds__(448, 4) void k1_conv1(const float* __restrict__ x,
        const float* __restrict__ sgn1, const float* __restrict__ b1,
        const float* __restrict__ g, const float* __restrict__ be,
        const float* __restrict__ mu, const float* __restrict__ va,
        ULL* __restrict__ qact1) {
    __shared__ float limg[30 * 30];   // limg[(x+1)*30 + (y+1)], borders zero
    int b = blockIdx.x, t = threadIdx.x;
    int wave = t >> 6, lane = t & 63;
    for (int i = t; i < 900; i += 448) limg[i] = 0.f;
    __syncthreads();
    const float* xb = x + (size_t)b * 784;
    for (int i = t; i < 784; i += 448) {
        int y = i / 28, xx = i - y * 28;
        limg[(xx + 1) * 30 + (y + 1)] = xb[i];   // transposed store
    }
    float w[9];
    #pragma unroll
    for (int k = 0; k < 9; ++k) w[k] = sgn1[lane * 9 + k];
    double iv = (double)g[lane] / sqrt((double)va[lane] + 1e-5);
    double cd = (double)be[lane] - (double)mu[lane] * iv;
    double bd = (double)b1[lane];
    // exact float threshold: pred(m) = ((double)m + bd)*iv + cd >= 0  (monotone in m)
    float am, Tf;
    if (iv > 0.0) {
        float c = (float)(-cd / iv - bd);
        for (int it = 0; it < 100 && !(((double)c + bd) * iv + cd >= 0.0); ++it)
            c = nextafterf(c, 3.4e38f);
        for (int it = 0; it < 100; ++it) {
            float d = nextafterf(c, -3.4e38f);
            if (((double)d + bd) * iv + cd >= 0.0) c = d; else break;
        }
        am = 1.f; Tf = c;                 // pred <=> m >= c
    } else if (iv < 0.0) {
        float c = (float)(-cd / iv - bd);
        for (int it = 0; it < 100 && !(((double)c + bd) * iv + cd >= 0.0); ++it)
            c = nextafterf(c, -3.4e38f);
        for (int it = 0; it < 100; ++it) {
            float d = nextafterf(c, 3.4e38f);
            if (((double)d + bd) * iv + cd >= 0.0) c = d; else break;
        }
        am = -1.f; Tf = -c;               // pred <=> m <= c <=> -m >= -c
    } else {
        am = 0.f; Tf = (cd >= 0.0) ? -1.f : 1.f;   // pred constant: +-0 >= -1 / >= 1
    }
    __syncthreads();

    #pragma unroll
    for (int rr = 0; rr < 2; ++rr) {
        int py = wave + rr * 7;           // pool row 0..13
        const float* base = &limg[2 * py];
        #pragma unroll
        for (int px = 0; px < 14; ++px) {
            float a00 = 0.f, a01 = 0.f, a10 = 0.f, a11 = 0.f;
            #pragma unroll
            for (int ky = 0; ky < 3; ++ky) {
                #pragma unroll
                for (int kx = 0; kx < 3; ++kx) {
                    float sv = w[ky * 3 + kx];
                    a00 = fmaf(base[(2 * px + kx)     * 30 + ky],     sv, a00);
                    a01 = fmaf(base[(2 * px + kx + 1) * 30 + ky],     sv, a01);
                    a10 = fmaf(base[(2 * px + kx)     * 30 + ky + 1], sv, a10);
                    a11 = fmaf(base[(2 * px + kx + 1) * 30 + ky + 1], sv, a11);
                }
            }
            float m = fmaxf(fmaxf(a00, a01), fmaxf(a10, a11));
            ULL word = __ballot(am * m >= Tf);
            if (lane == 0) qact1[(size_t)b * 196 + py * 14 + px] = word;
        }
    }
}

// ---------------- k2 v5: conv2 + maxpool + bn2 + binarize -> qact2 bits ----------------
// ONE WAVE per SAMPLE; no LDS/barriers; register window with compile-time slot rotation.
__global__ __launch_bounds__(256, 1) void k2_conv2(const ULL* __restrict__ qact1,
        const ULL* __restrict__ wb2, const float* __restrict__ b2,
        const float* __restrict__ g, const float* __restrict__ be,
        const float* __restrict__ mu, const float* __restrict__ va,
        ULL* __restrict__ qact2) {
    int lane = threadIdx.x & 63;
    int s = blockIdx.x * 4 + (threadIdx.x >> 6);   // sample id

    ULL wk[9];
    #pragma unroll
    for (int k = 0; k < 9; ++k) wk[k] = wb2[lane * 9 + k];
    int pw[9];
    #pragma unroll
    for (int k = 0; k < 9; ++k) pw[k] = 64 - 2 * (int)__popcll(wk[k]);

    double iv   = (double)g[lane] / sqrt((double)va[lane] + 1e-5);
    double cc   = (double)be[lane] - (double)mu[lane] * iv;
    double bias = (double)b2[lane];
    int am, thr;
    if (iv > 0.0) {
        double t0 = -cc / iv - bias;
        int c = (t0 < -590.0) ? -590 : (t0 > 590.0 ? 590 : (int)floor(t0) - 2);
        if (c < -590) c = -590;
        while (c <= 590 && !(((double)c + bias) * iv + cc >= 0.0)) ++c;
        am = 1; thr = c;
    } else if (iv < 0.0) {
        double t0 = -cc / iv - bias;
        int c = (t0 > 590.0) ? 590 : (t0 < -590.0 ? -590 : (int)ceil(t0) + 2);
        if (c > 590) c = 590;
        while (c >= -590 && !(((double)c + bias) * iv + cc >= 0.0)) --c;
        am = -1; thr = c;
    } else {
        am = 1; thr = (cc >= 0.0) ? -1000000 : 1000000;
    }
    int athr = am * thr;

    int cLs = pw[0] + pw[3] + pw[6], cRs = pw[2] + pw[5] + pw[8];
    int rT  = pw[0] + pw[1] + pw[2], rB  = pw[6] + pw[7] + pw[8];
    int tL = cLs + rT - pw[0], tM = rT, tR = cRs + rT - pw[2];
    int bL = cLs + rB - pw[6], bM = rB, bR = cRs + rB - pw[8];

    const ULL* base = qact1 + (size_t)s * 196;
    ULL cw[4][4];

    #pragma unroll 1
    for (int pr = 0; pr < 7; ++pr) {
        int r0 = 2 * pr;
        bool tpad = (pr == 0), bpad = (pr == 6);
        const ULL* rA = base + (tpad ? 0 : (r0 - 1) * 14);
        const ULL* rB_ = base + r0 * 14;
        const ULL* rC = base + (r0 + 1) * 14;
        const ULL* rD = base + (bpad ? 0 : (r0 + 2) * 14);
        ULL mT = tpad ? 0ULL : ~0ULL;
        ULL mB = bpad ? 0ULL : ~0ULL;
        int c00 = tpad ? tL : cLs, c01 = tpad ? tM : 0, c02 = tpad ? tR : cRs;
        int c10 = bpad ? bL : cLs, c11 = bpad ? bM : 0, c12 = bpad ? bR : cRs;

        #pragma unroll
        for (int r = 0; r < 4; ++r) cw[0][r] = 0ULL;
        #pragma unroll
        for (int c = 0; c < 3; ++c) {
            cw[c + 1][0] = rA[c] & mT;
            cw[c + 1][1] = rB_[c];
            cw[c + 1][2] = rC[c];
            cw[c + 1][3] = rD[c] & mB;
        }

        #pragma unroll
        for (int px = 0; px < 7; ++px) {
            int s00 = 0, s01 = 0, s10 = 0, s11 = 0;
            #pragma unroll
            for (int ky = 0; ky < 3; ++ky) {
                #pragma unroll
                for (int kx = 0; kx < 3; ++kx) {
                    ULL w = wk[ky * 3 + kx];
                    s00 += (int)__popcll(cw[(2 * px + kx)     & 3][ky    ] ^ w);
                    s01 += (int)__popcll(cw[(2 * px + kx + 1) & 3][ky    ] ^ w);
                    s10 += (int)__popcll(cw[(2 * px + kx)     & 3][ky + 1] ^ w);
                    s11 += (int)__popcll(cw[(2 * px + kx + 1) & 3][ky + 1] ^ w);
                }
            }
            int d00 = 576 - 2 * s00 - ((px == 0) ? c00 : c01);
            int d01 = 576 - 2 * s01 - ((px == 6) ? c02 : c01);
            int d10 = 576 - 2 * s10 - ((px == 0) ? c10 : c11);
            int d11 = 576 - 2 * s11 - ((px == 6) ? c12 : c11);
            int m = max(max(d00, d01), max(d10, d11));
            ULL word = __ballot(am * m >= athr);
            if (lane == 0) qact2[(size_t)s * 49 + pr * 7 + px] = word;

            if (px < 6) {
                const int n1 = 2 * px + 3, n2 = 2 * px + 4;
                cw[(n1 + 1) & 3][0] = rA[n1] & mT;
                cw[(n1 + 1) & 3][1] = rB_[n1];
                cw[(n1 + 1) & 3][2] = rC[n1];
                cw[(n1 + 1) & 3][3] = rD[n1] & mB;
                if (n2 <= 13) {
                    cw[(n2 + 1) & 3][0] = rA[n2] & mT;
                    cw[(n2 + 1) & 3][1] = rB_[n2];
                    cw[(n2 + 1) & 3][2] = rC[n2];
                    cw[(n2 + 1) & 3][3] = rD[n2] & mB;
                } else {
                    #pragma unroll
                    for (int r = 0; r < 4; ++r) cw[(n2 + 1) & 3][r] = 0ULL;
                }
            }
        }
    }
}

// ---------------- k3 v2: fc1 + bn3 + binarize -> hbits ----------------
// xs TRANSPOSED to [p][i] so the 16 sample-words per p are contiguous -> 8 ds_read_b128
// per p (was 16 ds_read_b64). Epilogue via exact integer threshold (dot in [-3136,3136]).
__global__ __launch_bounds__(256) void k3_fc1(const ULL* __restrict__ qact2,
        const ULL* __restrict__ wbT, const float* __restrict__ fb,
        const float* __restrict__ g, const float* __restrict__ be,
        const float* __restrict__ mu, const float* __restrict__ va,
        ULL* __restrict__ hbits) {
    __shared__ __align__(16) ULL xs[784];   // xs[p*16 + i], p=0..48, i=0..15
    int t = threadIdx.x, wave = t >> 6, lane = t & 63;
    int b0 = blockIdx.x * 16;
    int gidx = blockIdx.y * 4 + wave;   // 0..31
    int n = gidx * 64 + lane;
    for (int idx = t; idx < 784; idx += 256) {
        int p = idx >> 4, i = idx & 15;
        xs[idx] = qact2[(size_t)(b0 + i) * 49 + p];
    }
    double iv   = (double)g[n] / sqrt((double)va[n] + 1e-5);
    double cc   = (double)be[n] - (double)mu[n] * iv;
    double bias = (double)fb[n];
    int am, athr;
    {
        int amm, thr;
        if (iv > 0.0) {
            double t0 = -cc / iv - bias;
            int c = (t0 < -3200.0) ? -3200 : (t0 > 3200.0 ? 3200 : (int)floor(t0) - 2);
            if (c < -3200) c = -3200;
            int it = 0;
            while (c <= 3200 && !(((double)c + bias) * iv + cc >= 0.0) && it++ < 32) ++c;
            amm = 1; thr = c;
        } else if (iv < 0.0) {
            double t0 = -cc / iv - bias;
            int c = (t0 > 3200.0) ? 3200 : (t0 < -3200.0 ? -3200 : (int)ceil(t0) + 2);
            if (c > 3200) c = 3200;
            int it = 0;
            while (c >= -3200 && !(((double)c + bias) * iv + cc >= 0.0) && it++ < 32) --c;
            amm = -1; thr = c;
        } else {
            amm = 1; thr = (cc >= 0.0) ? -1000000 : 1000000;
        }
        am = amm; athr = amm * thr;
    }
    __syncthreads();
    int acc[16];
    #pragma unroll
    for (int i = 0; i < 16; ++i) acc[i] = 0;
    for (int p = 0; p < 49; ++p) {
        ULL w = wbT[p * 2048 + n];
        #pragma unroll
        for (int j = 0; j < 8; ++j) {
            ulonglong2 xv = *(const ulonglong2*)&xs[p * 16 + 2 * j];
            acc[2 * j]     += (int)__popcll(xv.x ^ w);
            acc[2 * j + 1] += (int)__popcll(xv.y ^ w);
        }
    }
    #pragma unroll
    for (int i = 0; i < 16; ++i) {
        int dot = 3136 - 2 * acc[i];
        ULL word = __ballot(am * dot >= athr);
        if (lane == 0) hbits[(size_t)(b0 + i) * 32 + gidx] = word;
    }
}

// ---------------- k4: fc2 + scale ----------------
__global__ __launch_bounds__(256) void k4_fc2(const ULL* __restrict__ hbits,
        const ULL* __restrict__ wbf2, const float* __restrict__ b2,
        const float* __restrict__ scale, float* __restrict__ out, int total) {
    int gid = blockIdx.x * 256 + threadIdx.x;
    if (gid >= total) return;
    int b = gid / 10, n = gid - b * 10;
    const ULL* h = hbits + (size_t)b * 32;
    const ULL* w = wbf2 + n * 32;
    int acc = 0;
    #pragma unroll
    for (int k = 0; k < 32; ++k) acc += (int)__popcll(h[k] ^ w[k]);
    int dot = 2048 - 2 * acc;
    double v = ((double)dot + (double)b2[n]) * (double)scale[0];
    out[gid] = (float)v;
}

// ---------------- launch ----------------
extern "C" void kernel_launch(void* const* d_in, const int* in_sizes, int n_in,
                              void* d_out, int out_size, void* d_ws, size_t ws_size,
                              hipStream_t stream) {
    const float* x      = (const float*)d_in[0];
    const float* w1     = (const float*)d_in[1];
    const float* b1     = (const float*)d_in[2];
    const float* w2     = (const float*)d_in[3];
    const float* b2     = (const float*)d_in[4];
    const float* fc1w   = (const float*)d_in[5];
    const float* fc1b   = (const float*)d_in[6];
    const float* fc2w   = (const float*)d_in[7];
    const float* fc2b   = (const float*)d_in[8];
    const float* g1 = (const float*)d_in[9],  *be1 = (const float*)d_in[10],
               *mu1 = (const float*)d_in[11], *va1 = (const float*)d_in[12];
    const float* g2 = (const float*)d_in[13], *be2 = (const float*)d_in[14],
               *mu2 = (const float*)d_in[15], *va2 = (const float*)d_in[16];
    const float* g3 = (const float*)d_in[17], *be3 = (const float*)d_in[18],
               *mu3 = (const float*)d_in[19], *va3 = (const float*)d_in[20];
    const float* scale = (const float*)d_in[21];
    float* out = (float*)d_out;

    int B = in_sizes[0] / 784;   // 4096

    // workspace layout (8B aligned)
    char* ws = (char*)d_ws;
    ULL* qact1 = (ULL*)(ws);                              // B*196 words
    ULL* qact2 = (ULL*)(ws + (size_t)B * 196 * 8);        // B*49 words
    ULL* hbits = (ULL*)(ws + (size_t)B * 245 * 8);        // B*32 words
    char* wsw  = ws + (size_t)B * 277 * 8;
    ULL* wb2   = (ULL*)(wsw);                             // 576 words
    ULL* wbT   = (ULL*)(wsw + 576 * 8);                   // 49*2048 words
    ULL* wbf2  = (ULL*)(wsw + 576 * 8 + 49 * 2048 * 8);   // 320 words
    float* sgn1 = (float*)(wsw + 576 * 8 + 49 * 2048 * 8 + 320 * 8); // 576 floats

    prep_small<<<227, 256, 0, stream>>>(w1, w2, fc2w, sgn1, wb2, wbf2);
    prep_pack_fc1<<<512, 256, 0, stream>>>(fc1w, wbT);   // 512 blocks x 4 rows = 2048

    k1_conv1<<<B, 448, 0, stream>>>(x, sgn1, b1, g1, be1, mu1, va1, qact1);
    k2_conv2<<<B / 4, 256, 0, stream>>>(qact1, wb2, b2, g2, be2, mu2, va2, qact2);
    k3_fc1<<<dim3(B / 16, 8), 256, 0, stream>>>(qact2, wbT, fc1b, g3, be3, mu3, va3, hbits);
    int total = B * 10;
    k4_fc2<<<(total + 255) / 256, 256, 0, stream>>>(hbits, wbf2, fc2b, scale, out, total);
}